// Round 2
// baseline (209.733 us; speedup 1.0000x reference)
//
#include <hip/hip_runtime.h>

// ComplexMultiheadAttention, MI355X/gfx950.
// Pipeline: cvt(f32->bf16) -> proj GEMMs (qr,qi,kr,ki,vr^T) -> banded flash attn -> out proj.
// B=2, L=4096, E=512, H=8, D=64, W=128 (mask: j <= i-129 is -inf; NO causal/upper mask).

typedef unsigned short u16;
typedef unsigned int u32;
typedef __attribute__((ext_vector_type(8))) short bf16x8;
typedef __attribute__((ext_vector_type(4))) float f32x4;
typedef __attribute__((ext_vector_type(16))) float f32x16;
typedef __attribute__((ext_vector_type(4))) u32 u32x4;

#define L_ 4096
#define E_ 512
#define M_ 8192  // B*L

__device__ __forceinline__ u16 f2bf(float f) {
  union { float f; u32 u; } v; v.f = f;
  return (u16)((v.u + 0x7FFFu + ((v.u >> 16) & 1u)) >> 16);  // RNE
}

__device__ __forceinline__ void gll16(const void* g, void* l) {
  __builtin_amdgcn_global_load_lds(
      (const __attribute__((address_space(1))) u32*)g,
      (__attribute__((address_space(3))) u32*)l, 16, 0, 0);
}

// ---------------- conversion kernels ----------------
__global__ void cvt_x_kernel(const float* __restrict__ q, const float* __restrict__ k,
                             const float* __restrict__ v,
                             u16* __restrict__ xq, u16* __restrict__ xk, u16* __restrict__ xv) {
  const int total = 3 * (M_ * E_ / 4);  // float4 units, 1<<20 per matrix
  int stride = gridDim.x * blockDim.x;
  for (int u = blockIdx.x * blockDim.x + threadIdx.x; u < total; u += stride) {
    int mat = u >> 20, e = u & ((1 << 20) - 1);
    const float4 f = ((const float4*)(mat == 0 ? q : mat == 1 ? k : v))[e];
    ushort4 o = make_ushort4(f2bf(f.x), f2bf(f.y), f2bf(f.z), f2bf(f.w));
    *(ushort4*)((mat == 0 ? xq : mat == 1 ? xk : xv) + (size_t)e * 4) = o;
  }
}

struct CPtrs { const float* w[7]; const float* b[7]; };

__global__ void cvt_wb_kernel(CPtrs p, u16* __restrict__ wcat, float* __restrict__ bcat) {
  // wcat rows: [qWr|qWi|kWr|kWi|vWr|oWr|oWi], each 512x512. bcat matching biases.
  const int total = 7 * (E_ * E_ / 4);  // 65536 float4 per matrix
  int stride = gridDim.x * blockDim.x;
  int t0 = blockIdx.x * blockDim.x + threadIdx.x;
  for (int u = t0; u < total; u += stride) {
    int wi = u >> 16, e = u & 65535;
    const float4 f = ((const float4*)p.w[wi])[e];
    ushort4 o = make_ushort4(f2bf(f.x), f2bf(f.y), f2bf(f.z), f2bf(f.w));
    *(ushort4*)(wcat + (size_t)wi * 262144 + (size_t)e * 4) = o;
  }
  for (int j = t0; j < 3584; j += stride) bcat[j] = p.b[j >> 9][j & 511];
}

// ---------------- 128x128 bf16 GEMM mainloop (C = A @ W^T), K=512, BK=32 ----------------
__device__ __forceinline__ void gemm128_main(const u16* __restrict__ A, const u16* __restrict__ Bw,
                                             int m0, int n0w, char* sm, f32x4 acc[4][4]) {
  int tid = threadIdx.x;
  int lane = tid & 63, w = tid >> 6;
  int wm = w >> 1, wn = w & 1;
#pragma unroll
  for (int a = 0; a < 4; a++)
#pragma unroll
    for (int b = 0; b < 4; b++)
#pragma unroll
      for (int j = 0; j < 4; j++) acc[a][b][j] = 0.f;

  auto stage = [&](int buf, int ks) {
    char* dst = sm + buf * 16384;
#pragma unroll
    for (int n = 0; n < 2; n++) {
      int u = n * 256 + tid;
      int row = u >> 2, c = u & 3;
      int so = (c ^ (row & 3)) * 16;  // pre-swizzled source chunk (LDS stays linear)
      int ldso = (n * 256 + w * 64) * 16;
      gll16((const char*)(A + (size_t)(m0 + row) * 512 + ks * 32) + so, dst + ldso);
      gll16((const char*)(Bw + (size_t)(n0w + row) * 512 + ks * 32) + so, dst + 8192 + ldso);
    }
  };

  stage(0, 0);
  __syncthreads();
  int cur = 0;
  for (int ks = 0; ks < 16; ks++) {
    if (ks < 15) stage(cur ^ 1, ks + 1);
    const char* as = sm + cur * 16384;
    const char* bs = as + 8192;
    bf16x8 af[4], bfr[4];
#pragma unroll
    for (int i = 0; i < 4; i++) {
      int ra = wm * 64 + i * 16 + (lane & 15);
      af[i] = *(const bf16x8*)(as + ra * 64 + (((lane >> 4) * 16) ^ ((ra & 3) << 4)));
      int rb = wn * 64 + i * 16 + (lane & 15);
      bfr[i] = *(const bf16x8*)(bs + rb * 64 + (((lane >> 4) * 16) ^ ((rb & 3) << 4)));
    }
#pragma unroll
    for (int mt = 0; mt < 4; mt++)
#pragma unroll
      for (int nt = 0; nt < 4; nt++)
        acc[mt][nt] = __builtin_amdgcn_mfma_f32_16x16x32_bf16(af[mt], bfr[nt], acc[mt][nt], 0, 0, 0);
    __syncthreads();
    cur ^= 1;
  }
}

// ---------------- projection kernel (q,k,v jobs) ----------------
__global__ __launch_bounds__(256) void proj_kernel(
    const u16* __restrict__ xq, const u16* __restrict__ xk, const u16* __restrict__ xv,
    const u16* __restrict__ wcat, const float* __restrict__ bcat,
    u16* __restrict__ qrb, u16* __restrict__ qib,
    u16* __restrict__ krb, u16* __restrict__ kib, u16* __restrict__ vtb) {
  __shared__ alignas(16) char sm[32768];
  int bx = blockIdx.x, by = blockIdx.y;  // bx<8: q (N=1024), bx<16: k, else v (N=512)
  const u16* A = bx < 8 ? xq : (bx < 16 ? xk : xv);
  int m0 = by * 128, n0w = bx * 128;
  f32x4 acc[4][4];
  gemm128_main(A, wcat, m0, n0w, sm, acc);

  int lane = threadIdx.x & 63, w = threadIdx.x >> 6;
  int wm = w >> 1, wn = w & 1;
  int lL = lane & 15, lH = lane >> 4;
#pragma unroll
  for (int mt = 0; mt < 4; mt++) {
#pragma unroll
    for (int nt = 0; nt < 4; nt++) {
      int n = n0w + wn * 64 + nt * 16 + lL;  // global wcat row
      float bias = bcat[n];
      int e = n & 511;
#pragma unroll
      for (int j = 0; j < 4; j++) {
        int m = m0 + wm * 64 + mt * 16 + lH * 4 + j;
        float val = acc[mt][nt][j] + bias;
        int bb = m >> 12, ll = m & 4095;
        if (bx < 16) {
          if (bx < 8) val *= 0.125f;  // fold 1/sqrt(D) into q
          u16* dst = (bx < 8) ? ((n & 512) ? qib : qrb) : ((n & 512) ? kib : krb);
          dst[((size_t)((bb * 8 + (e >> 6)) * 4096 + ll) << 6) + (e & 63)] = f2bf(val);
        } else {
          // vr stored transposed: VT[bh][d][l]
          vtb[((size_t)((bb * 8 + (e >> 6)) * 64 + (e & 63)) << 12) + ll] = f2bf(val);
        }
      }
    }
  }
}

// ---------------- output projection kernel ----------------
__global__ __launch_bounds__(256) void oproj_kernel(
    const u16* __restrict__ obf, const u16* __restrict__ wcat, const float* __restrict__ bcat,
    float* __restrict__ out) {
  __shared__ alignas(16) char sm[32768];
  int bx = blockIdx.x, by = blockIdx.y;
  int m0 = by * 128, n0w = 2560 + bx * 128;
  f32x4 acc[4][4];
  gemm128_main(obf, wcat, m0, n0w, sm, acc);

  int lane = threadIdx.x & 63, w = threadIdx.x >> 6;
  int wm = w >> 1, wn = w & 1;
  int lL = lane & 15, lH = lane >> 4;
#pragma unroll
  for (int mt = 0; mt < 4; mt++) {
#pragma unroll
    for (int nt = 0; nt < 4; nt++) {
      int n = n0w + wn * 64 + nt * 16 + lL;
      float bias = bcat[n];
      int nn = n - 2560;
      // out_r at [0, 4194304), out_i at [4194304, 8388608)  (B*L*E = 4194304 each)
      float* dst = out + ((nn & 512) ? 4194304 : 0) + (nn & 511);
#pragma unroll
      for (int j = 0; j < 4; j++) {
        int m = m0 + wm * 64 + mt * 16 + lH * 4 + j;
        dst[(size_t)m * 512] = acc[mt][nt][j] + bias;
      }
    }
  }
}

// ---------------- banded flash attention ----------------
// QB=64 (2 waves x 32 q-rows), KB=64, D=64. Swapped QK^T: S^T = mfma(K, Q).
// S^T layout (32x32x16): col=lane&31 (=q), row=(r&3)+8*(r>>2)+4*(lane>>5) (=k).
__global__ __launch_bounds__(128) void attn_kernel(
    const u16* __restrict__ qrb, const u16* __restrict__ qib,
    const u16* __restrict__ krb, const u16* __restrict__ kib,
    const u16* __restrict__ vtb, u16* __restrict__ obf) {
  __shared__ alignas(16) char sm[2 * 24576];  // dbuf x (Kr 8K | Ki 8K | VT 8K)
  int bid = blockIdx.x;
  int bh = bid & 15, qt = bid >> 4;  // bh pins to XCD (bid%8==bh%8); qt ascending = work descending
  int bb = bh >> 3, hh = bh & 7;
  int i0 = qt << 6;
  int tid = threadIdx.x;
  int lane = tid & 63, w = tid >> 6;
  int lo = lane & 31, hi = lane >> 5;
  int i0w = i0 + w * 32;
  int irow = i0w + lo;

  // Q fragments (B-operand): lane holds Q[q=lo][d = c*16 + hi*8 + i]
  bf16x8 fqr[4], fqi[4];
  {
    const u16* qp = qrb + ((size_t)(bh * 4096 + irow) << 6) + hi * 8;
    const u16* qip = qib + ((size_t)(bh * 4096 + irow) << 6) + hi * 8;
#pragma unroll
    for (int c = 0; c < 4; c++) {
      fqr[c] = *(const bf16x8*)(qp + c * 16);
      fqi[c] = *(const bf16x8*)(qip + c * 16);
    }
  }

  f32x16 oa0, oa1;  // O^T[d][q]: oa0 d=0..31, oa1 d=32..63 (col=q=lo)
#pragma unroll
  for (int r = 0; r < 16; r++) { oa0[r] = 0.f; oa1[r] = 0.f; }
  float m_run = -1e30f, l_run = 0.f;

  int jstart = (i0 >= 128) ? (i0 - 128) : 0;
  int ntiles = (4096 - jstart) >> 6;

  auto stage = [&](int buf, int j0) {
    char* dst = sm + buf * 24576;
#pragma unroll
    for (int n = 0; n < 4; n++) {
      int u = n * 128 + tid;
      int row = u >> 3, c = u & 7;
      int so = (c ^ (row & 7)) * 16;  // pre-swizzled source; LDS linear
      int ldso = (n * 128 + w * 64) * 16;
      size_t krow = ((size_t)(bh * 4096 + j0 + row) << 6);
      gll16((const char*)(krb + krow) + so, dst + ldso);
      gll16((const char*)(kib + krow) + so, dst + 8192 + ldso);
      size_t vrow = ((size_t)(bh * 64 + row) << 12) + j0;
      gll16((const char*)(vtb + vrow) + so, dst + 16384 + ldso);
    }
  };

  auto cvtpk = [](float a, float b) -> u32 {
    u32 r;
    asm("v_cvt_pk_bf16_f32 %0, %1, %2" : "=v"(r) : "v"(a), "v"(b));
    return r;
  };
  auto mkfrag = [&](const float* p, bf16x8& fA, bf16x8& fB) {
    u32 x0 = cvtpk(p[0], p[1]), y0 = cvtpk(p[4], p[5]);
    u32 x1 = cvtpk(p[2], p[3]), y1 = cvtpk(p[6], p[7]);
    u32 x2 = cvtpk(p[8], p[9]), y2 = cvtpk(p[12], p[13]);
    u32 x3 = cvtpk(p[10], p[11]), y3 = cvtpk(p[14], p[15]);
    asm("v_permlane32_swap_b32 %0, %1" : "+v"(x0), "+v"(y0));
    asm("v_permlane32_swap_b32 %0, %1" : "+v"(x1), "+v"(y1));
    asm("v_permlane32_swap_b32 %0, %1" : "+v"(x2), "+v"(y2));
    asm("v_permlane32_swap_b32 %0, %1" : "+v"(x3), "+v"(y3));
    u32x4 a; a[0] = x0; a[1] = x1; a[2] = y0; a[3] = y1;
    u32x4 b; b[0] = x2; b[1] = x3; b[2] = y2; b[3] = y3;
    fA = __builtin_bit_cast(bf16x8, a);
    fB = __builtin_bit_cast(bf16x8, b);
  };

  stage(0, jstart);
  __syncthreads();
  int cur = 0;
  int swz = (lo & 7) << 4;

  for (int t = 0; t < ntiles; t++) {
    int j0 = jstart + (t << 6);
    if (t + 1 < ntiles) stage(cur ^ 1, j0 + 64);
    const char* Kr = sm + cur * 24576;
    const char* Ki = Kr + 8192;
    const char* Vt = Kr + 16384;

    // S^T = Kr@Qr^T + Ki@Qi^T  (two 32-k tiles)
    f32x16 s0, s1;
#pragma unroll
    for (int r = 0; r < 16; r++) { s0[r] = 0.f; s1[r] = 0.f; }
#pragma unroll
    for (int c = 0; c < 4; c++) {
      int off = (c * 32 + hi * 16) ^ swz;
      bf16x8 a0r = *(const bf16x8*)(Kr + lo * 128 + off);
      bf16x8 a0i = *(const bf16x8*)(Ki + lo * 128 + off);
      bf16x8 a1r = *(const bf16x8*)(Kr + (32 + lo) * 128 + off);
      bf16x8 a1i = *(const bf16x8*)(Ki + (32 + lo) * 128 + off);
      s0 = __builtin_amdgcn_mfma_f32_32x32x16_bf16(a0r, fqr[c], s0, 0, 0, 0);
      s0 = __builtin_amdgcn_mfma_f32_32x32x16_bf16(a0i, fqi[c], s0, 0, 0, 0);
      s1 = __builtin_amdgcn_mfma_f32_32x32x16_bf16(a1r, fqr[c], s1, 0, 0, 0);
      s1 = __builtin_amdgcn_mfma_f32_32x32x16_bf16(a1i, fqi[c], s1, 0, 0, 0);
    }
    // banded mask: k <= i-129 -> -inf   (only ever the first tile of a block)
    if (j0 <= i0w - 98) {
#pragma unroll
      for (int r = 0; r < 16; r++) {
        int kk = j0 + (r & 3) + ((r >> 2) << 3) + (hi << 2);
        if (kk <= irow - 129) s0[r] = -3e38f;
        if (kk + 32 <= irow - 129) s1[r] = -3e38f;
      }
    }
    // online softmax, all state lane-local (lane owns q=lo; partner lane l^32 mirrors)
    float pmax = s0[0];
#pragma unroll
    for (int r = 1; r < 16; r++) pmax = fmaxf(pmax, s0[r]);
#pragma unroll
    for (int r = 0; r < 16; r++) pmax = fmaxf(pmax, s1[r]);
    pmax = fmaxf(pmax, __shfl_xor(pmax, 32));
    float mnew = fmaxf(m_run, pmax);
    float scl = __expf(m_run - mnew);
    float p0[16], p1[16];
    float psum = 0.f;
#pragma unroll
    for (int r = 0; r < 16; r++) { p0[r] = __expf(s0[r] - mnew); psum += p0[r]; }
#pragma unroll
    for (int r = 0; r < 16; r++) { p1[r] = __expf(s1[r] - mnew); psum += p1[r]; }
    psum += __shfl_xor(psum, 32);
    l_run = l_run * scl + psum;
    m_run = mnew;
#pragma unroll
    for (int r = 0; r < 16; r++) { oa0[r] *= scl; oa1[r] *= scl; }

    // assemble P^T B-fragments in-register (cvt_pk + permlane32_swap)
    bf16x8 pf0, pf1, pf2, pf3;
    mkfrag(p0, pf0, pf1);
    mkfrag(p1, pf2, pf3);

    // O^T += V^T @ P^T
#pragma unroll
    for (int kc = 0; kc < 4; kc++) {
      int off = (kc * 32 + hi * 16) ^ swz;
      bf16x8 av0 = *(const bf16x8*)(Vt + lo * 128 + off);
      bf16x8 av1 = *(const bf16x8*)(Vt + (32 + lo) * 128 + off);
      bf16x8 pk = (kc == 0) ? pf0 : (kc == 1) ? pf1 : (kc == 2) ? pf2 : pf3;
      oa0 = __builtin_amdgcn_mfma_f32_32x32x16_bf16(av0, pk, oa0, 0, 0, 0);
      oa1 = __builtin_amdgcn_mfma_f32_32x32x16_bf16(av1, pk, oa1, 0, 0, 0);
    }
    __syncthreads();
    cur ^= 1;
  }

  // write o[b][l][h*64+d] bf16; lane holds column q=lo of O^T
  float rl = 1.0f / l_run;
  u16* orow = obf + ((size_t)(bb * 4096 + irow) << 9) + hh * 64;
#pragma unroll
  for (int g = 0; g < 4; g++) {
    ushort4 v0 = make_ushort4(f2bf(oa0[4 * g] * rl), f2bf(oa0[4 * g + 1] * rl),
                              f2bf(oa0[4 * g + 2] * rl), f2bf(oa0[4 * g + 3] * rl));
    *(ushort4*)(orow + g * 8 + hi * 4) = v0;
    ushort4 v1 = make_ushort4(f2bf(oa1[4 * g] * rl), f2bf(oa1[4 * g + 1] * rl),
                              f2bf(oa1[4 * g + 2] * rl), f2bf(oa1[4 * g + 3] * rl));
    *(ushort4*)(orow + 32 + g * 8 + hi * 4) = v1;
  }
}

// ---------------- launch ----------------
extern "C" void kernel_launch(void* const* d_in, const int* in_sizes, int n_in,
                              void* d_out, int out_size, void* d_ws, size_t ws_size,
                              hipStream_t stream) {
  (void)in_sizes; (void)n_in; (void)out_size; (void)ws_size;
  const float* q = (const float*)d_in[0];
  const float* k = (const float*)d_in[1];
  const float* v = (const float*)d_in[2];
  char* ws = (char*)d_ws;
  u16* wcat = (u16*)(ws + 0x000000);     // 3584x512 bf16
  float* bcat = (float*)(ws + 0x400000); // 3584 f32
  u16* xq  = (u16*)(ws + 0x500000);
  u16* xk  = (u16*)(ws + 0xD00000);
  u16* xv  = (u16*)(ws + 0x1500000);
  u16* qrb = (u16*)(ws + 0x1D00000);
  u16* qib = (u16*)(ws + 0x2500000);
  u16* krb = (u16*)(ws + 0x2D00000);
  u16* kib = (u16*)(ws + 0x3500000);
  u16* vtb = (u16*)(ws + 0x3D00000);
  u16* obf = xq;  // xq dead after proj; reuse for attention output
  float* out = (float*)d_out;

  cvt_x_kernel<<<2048, 256, 0, stream>>>(q, k, v, xq, xk, xv);

  CPtrs cp;
  cp.w[0] = (const float*)d_in[3];  cp.w[1] = (const float*)d_in[4];
  cp.w[2] = (const float*)d_in[7];  cp.w[3] = (const float*)d_in[8];
  cp.w[4] = (const float*)d_in[11]; cp.w[5] = (const float*)d_in[15]; cp.w[6] = (const float*)d_in[16];
  cp.b[0] = (const float*)d_in[5];  cp.b[1] = (const float*)d_in[6];
  cp.b[2] = (const float*)d_in[9];  cp.b[3] = (const float*)d_in[10];
  cp.b[4] = (const float*)d_in[13]; cp.b[5] = (const float*)d_in[17]; cp.b[6] = (const float*)d_in[18];
  cvt_wb_kernel<<<448, 256, 0, stream>>>(cp, wcat, bcat);

  proj_kernel<<<dim3(20, 64), 256, 0, stream>>>(xq, xk, xv, wcat, bcat, qrb, qib, krb, kib, vtb);
  attn_kernel<<<1024, 128, 0, stream>>>(qrb, qib, krb, kib, vtb, obf);
  oproj_kernel<<<dim3(8, 64), 256, 0, stream>>>(obf, wcat, bcat, out);
}

// Round 3
// 200.987 us; speedup vs baseline: 1.0435x; 1.0435x over previous
//
#include <hip/hip_runtime.h>

// ComplexMultiheadAttention, MI355X/gfx950.
// Pipeline: cvt(f32->bf16) -> proj GEMMs (qr,qi,kr,ki,vr^T) -> banded flash attn -> out proj.
// B=2, L=4096, E=512, H=8, D=64, W=128 (mask: j <= i-129 is -inf; NO causal/upper mask).
// Softmax runs in log2 domain: 0.125*log2(e) folded into q projection, exp2f in-kernel.

typedef unsigned short u16;
typedef unsigned int u32;
typedef __attribute__((ext_vector_type(8))) short bf16x8;
typedef __attribute__((ext_vector_type(4))) float f32x4;
typedef __attribute__((ext_vector_type(16))) float f32x16;
typedef __attribute__((ext_vector_type(4))) u32 u32x4;

#define L_ 4096
#define E_ 512
#define M_ 8192  // B*L

__device__ __forceinline__ u16 f2bf(float f) {
  union { float f; u32 u; } v; v.f = f;
  return (u16)((v.u + 0x7FFFu + ((v.u >> 16) & 1u)) >> 16);  // RNE
}

__device__ __forceinline__ void gll16(const void* g, void* l) {
  __builtin_amdgcn_global_load_lds(
      (const __attribute__((address_space(1))) u32*)g,
      (__attribute__((address_space(3))) u32*)l, 16, 0, 0);
}

// ---------------- conversion kernels ----------------
__global__ void cvt_x_kernel(const float* __restrict__ q, const float* __restrict__ k,
                             const float* __restrict__ v,
                             u16* __restrict__ xq, u16* __restrict__ xk, u16* __restrict__ xv) {
  const int total = 3 * (M_ * E_ / 4);  // float4 units, 1<<20 per matrix
  int stride = gridDim.x * blockDim.x;
  for (int u = blockIdx.x * blockDim.x + threadIdx.x; u < total; u += stride) {
    int mat = u >> 20, e = u & ((1 << 20) - 1);
    const float4 f = ((const float4*)(mat == 0 ? q : mat == 1 ? k : v))[e];
    ushort4 o = make_ushort4(f2bf(f.x), f2bf(f.y), f2bf(f.z), f2bf(f.w));
    *(ushort4*)((mat == 0 ? xq : mat == 1 ? xk : xv) + (size_t)e * 4) = o;
  }
}

struct CPtrs { const float* w[7]; const float* b[7]; };

__global__ void cvt_wb_kernel(CPtrs p, u16* __restrict__ wcat, float* __restrict__ bcat) {
  // wcat rows: [qWr|qWi|kWr|kWi|vWr|oWr|oWi], each 512x512. bcat matching biases.
  const int total = 7 * (E_ * E_ / 4);  // 65536 float4 per matrix
  int stride = gridDim.x * blockDim.x;
  int t0 = blockIdx.x * blockDim.x + threadIdx.x;
  for (int u = t0; u < total; u += stride) {
    int wi = u >> 16, e = u & 65535;
    const float4 f = ((const float4*)p.w[wi])[e];
    ushort4 o = make_ushort4(f2bf(f.x), f2bf(f.y), f2bf(f.z), f2bf(f.w));
    *(ushort4*)(wcat + (size_t)wi * 262144 + (size_t)e * 4) = o;
  }
  for (int j = t0; j < 3584; j += stride) bcat[j] = p.b[j >> 9][j & 511];
}

// ---------------- 128x128 bf16 GEMM mainloop (C = A @ W^T), K=512, BK=32 ----------------
__device__ __forceinline__ void gemm128_main(const u16* __restrict__ A, const u16* __restrict__ Bw,
                                             int m0, int n0w, char* sm, f32x4 acc[4][4]) {
  int tid = threadIdx.x;
  int lane = tid & 63, w = tid >> 6;
  int wm = w >> 1, wn = w & 1;
#pragma unroll
  for (int a = 0; a < 4; a++)
#pragma unroll
    for (int b = 0; b < 4; b++)
#pragma unroll
      for (int j = 0; j < 4; j++) acc[a][b][j] = 0.f;

  auto stage = [&](int buf, int ks) {
    char* dst = sm + buf * 16384;
#pragma unroll
    for (int n = 0; n < 2; n++) {
      int u = n * 256 + tid;
      int row = u >> 2, c = u & 3;
      int so = (c ^ (row & 3)) * 16;  // pre-swizzled source chunk (LDS stays linear)
      int ldso = (n * 256 + w * 64) * 16;
      gll16((const char*)(A + (size_t)(m0 + row) * 512 + ks * 32) + so, dst + ldso);
      gll16((const char*)(Bw + (size_t)(n0w + row) * 512 + ks * 32) + so, dst + 8192 + ldso);
    }
  };

  stage(0, 0);
  __syncthreads();
  int cur = 0;
  for (int ks = 0; ks < 16; ks++) {
    if (ks < 15) stage(cur ^ 1, ks + 1);
    const char* as = sm + cur * 16384;
    const char* bs = as + 8192;
    bf16x8 af[4], bfr[4];
#pragma unroll
    for (int i = 0; i < 4; i++) {
      int ra = wm * 64 + i * 16 + (lane & 15);
      af[i] = *(const bf16x8*)(as + ra * 64 + (((lane >> 4) * 16) ^ ((ra & 3) << 4)));
      int rb = wn * 64 + i * 16 + (lane & 15);
      bfr[i] = *(const bf16x8*)(bs + rb * 64 + (((lane >> 4) * 16) ^ ((rb & 3) << 4)));
    }
    __builtin_amdgcn_s_setprio(1);
#pragma unroll
    for (int mt = 0; mt < 4; mt++)
#pragma unroll
      for (int nt = 0; nt < 4; nt++)
        acc[mt][nt] = __builtin_amdgcn_mfma_f32_16x16x32_bf16(af[mt], bfr[nt], acc[mt][nt], 0, 0, 0);
    __builtin_amdgcn_s_setprio(0);
    __syncthreads();
    cur ^= 1;
  }
}

// ---------------- projection kernel (q,k,v jobs) ----------------
__global__ __launch_bounds__(256) void proj_kernel(
    const u16* __restrict__ xq, const u16* __restrict__ xk, const u16* __restrict__ xv,
    const u16* __restrict__ wcat, const float* __restrict__ bcat,
    u16* __restrict__ qrb, u16* __restrict__ qib,
    u16* __restrict__ krb, u16* __restrict__ kib, u16* __restrict__ vtb) {
  __shared__ alignas(16) char sm[32768];
  int bx = blockIdx.x, by = blockIdx.y;  // bx<8: q (N=1024), bx<16: k, else v (N=512)
  const u16* A = bx < 8 ? xq : (bx < 16 ? xk : xv);
  int m0 = by * 128, n0w = bx * 128;
  f32x4 acc[4][4];
  gemm128_main(A, wcat, m0, n0w, sm, acc);

  int lane = threadIdx.x & 63, w = threadIdx.x >> 6;
  int wm = w >> 1, wn = w & 1;
  int lL = lane & 15, lH = lane >> 4;
#pragma unroll
  for (int mt = 0; mt < 4; mt++) {
#pragma unroll
    for (int nt = 0; nt < 4; nt++) {
      int n = n0w + wn * 64 + nt * 16 + lL;  // global wcat row
      float bias = bcat[n];
      int e = n & 511;
#pragma unroll
      for (int j = 0; j < 4; j++) {
        int m = m0 + wm * 64 + mt * 16 + lH * 4 + j;
        float val = acc[mt][nt][j] + bias;
        int bb = m >> 12, ll = m & 4095;
        if (bx < 16) {
          if (bx < 8) val *= 0.18033688011112042f;  // 1/sqrt(D) * log2(e) folded into q
          u16* dst = (bx < 8) ? ((n & 512) ? qib : qrb) : ((n & 512) ? kib : krb);
          dst[((size_t)((bb * 8 + (e >> 6)) * 4096 + ll) << 6) + (e & 63)] = f2bf(val);
        } else {
          // vr stored transposed: VT[bh][d][l]
          vtb[((size_t)((bb * 8 + (e >> 6)) * 64 + (e & 63)) << 12) + ll] = f2bf(val);
        }
      }
    }
  }
}

// ---------------- output projection kernel ----------------
__global__ __launch_bounds__(256) void oproj_kernel(
    const u16* __restrict__ obf, const u16* __restrict__ wcat, const float* __restrict__ bcat,
    float* __restrict__ out) {
  __shared__ alignas(16) char sm[32768];
  int bx = blockIdx.x, by = blockIdx.y;
  int m0 = by * 128, n0w = 2560 + bx * 128;
  f32x4 acc[4][4];
  gemm128_main(obf, wcat, m0, n0w, sm, acc);

  int lane = threadIdx.x & 63, w = threadIdx.x >> 6;
  int wm = w >> 1, wn = w & 1;
  int lL = lane & 15, lH = lane >> 4;
#pragma unroll
  for (int mt = 0; mt < 4; mt++) {
#pragma unroll
    for (int nt = 0; nt < 4; nt++) {
      int n = n0w + wn * 64 + nt * 16 + lL;
      float bias = bcat[n];
      int nn = n - 2560;
      // out_r at [0, 4194304), out_i at [4194304, 8388608)  (B*L*E = 4194304 each)
      float* dst = out + ((nn & 512) ? 4194304 : 0) + (nn & 511);
#pragma unroll
      for (int j = 0; j < 4; j++) {
        int m = m0 + wm * 64 + mt * 16 + lH * 4 + j;
        dst[(size_t)m * 512] = acc[mt][nt][j] + bias;
      }
    }
  }
}

// ---------------- banded flash attention ----------------
// QB=128 (4 waves x 32 q-rows), KB=64, D=64. Swapped QK^T: S^T = mfma(K, Q).
// S^T layout (32x32x16): col=lane&31 (=q), row=(r&3)+8*(r>>2)+4*(lane>>5) (=k).
// Softmax in log2 domain (scale folded into q); defer-max with THR=11.5 (=e^8).
__global__ __launch_bounds__(256, 3) void attn_kernel(
    const u16* __restrict__ qrb, const u16* __restrict__ qib,
    const u16* __restrict__ krb, const u16* __restrict__ kib,
    const u16* __restrict__ vtb, u16* __restrict__ obf) {
  __shared__ alignas(16) char sm[2 * 24576];  // dbuf x (Kr 8K | Ki 8K | VT 8K)
  int bid = blockIdx.x;
  int bh = bid & 15;          // bh pins to XCD (bid%8==bh%8)
  int q2 = bid >> 4;          // 0..31
  int qt = (q2 < 16) ? q2 : (47 - q2);  // pair heavy+light blocks per CU (work ~const)
  int bb = bh >> 3, hh = bh & 7;
  int i0 = qt << 7;
  int tid = threadIdx.x;
  int lane = tid & 63, w = tid >> 6;    // w in 0..3
  int lo = lane & 31, hi = lane >> 5;
  int i0w = i0 + w * 32;
  int irow = i0w + lo;

  // Q fragments (B-operand): lane holds Q[q=lo][d = c*16 + hi*8 + i]
  bf16x8 fqr[4], fqi[4];
  {
    const u16* qp = qrb + ((size_t)(bh * 4096 + irow) << 6) + hi * 8;
    const u16* qip = qib + ((size_t)(bh * 4096 + irow) << 6) + hi * 8;
#pragma unroll
    for (int c = 0; c < 4; c++) {
      fqr[c] = *(const bf16x8*)(qp + c * 16);
      fqi[c] = *(const bf16x8*)(qip + c * 16);
    }
  }

  f32x16 oa0, oa1;  // O^T[d][q]: oa0 d=0..31, oa1 d=32..63 (col=q=lo)
#pragma unroll
  for (int r = 0; r < 16; r++) { oa0[r] = 0.f; oa1[r] = 0.f; }
  float m_run = -1e30f, l_run = 0.f;

  int jstart = (i0 >= 128) ? (i0 - 128) : 0;
  int ntiles = (4096 - jstart) >> 6;

  auto stage = [&](int buf, int j0) {
    char* dst = sm + buf * 24576;
#pragma unroll
    for (int n = 0; n < 2; n++) {
      int u = n * 256 + tid;           // 0..511 over 64 rows x 8 chunks
      int row = u >> 3, c = u & 7;
      int so = (c ^ (row & 7)) * 16;   // pre-swizzled source; LDS linear
      int ldso = (n * 256 + w * 64) * 16;  // wave-uniform LDS base
      size_t krow = ((size_t)(bh * 4096 + j0 + row) << 6);
      gll16((const char*)(krb + krow) + so, dst + ldso);
      gll16((const char*)(kib + krow) + so, dst + 8192 + ldso);
      size_t vrow = ((size_t)(bh * 64 + row) << 12) + j0;
      gll16((const char*)(vtb + vrow) + so, dst + 16384 + ldso);
    }
  };

  auto cvtpk = [](float a, float b) -> u32 {
    u32 r;
    asm("v_cvt_pk_bf16_f32 %0, %1, %2" : "=v"(r) : "v"(a), "v"(b));
    return r;
  };
  auto mkfrag = [&](const float* p, bf16x8& fA, bf16x8& fB) {
    u32 x0 = cvtpk(p[0], p[1]), y0 = cvtpk(p[4], p[5]);
    u32 x1 = cvtpk(p[2], p[3]), y1 = cvtpk(p[6], p[7]);
    u32 x2 = cvtpk(p[8], p[9]), y2 = cvtpk(p[12], p[13]);
    u32 x3 = cvtpk(p[10], p[11]), y3 = cvtpk(p[14], p[15]);
    asm("v_permlane32_swap_b32 %0, %1" : "+v"(x0), "+v"(y0));
    asm("v_permlane32_swap_b32 %0, %1" : "+v"(x1), "+v"(y1));
    asm("v_permlane32_swap_b32 %0, %1" : "+v"(x2), "+v"(y2));
    asm("v_permlane32_swap_b32 %0, %1" : "+v"(x3), "+v"(y3));
    u32x4 a; a[0] = x0; a[1] = x1; a[2] = y0; a[3] = y1;
    u32x4 b; b[0] = x2; b[1] = x3; b[2] = y2; b[3] = y3;
    fA = __builtin_bit_cast(bf16x8, a);
    fB = __builtin_bit_cast(bf16x8, b);
  };

  stage(0, jstart);
  __syncthreads();
  int cur = 0;
  int swz = (lo & 7) << 4;

  for (int t = 0; t < ntiles; t++) {
    int j0 = jstart + (t << 6);
    if (t + 1 < ntiles) stage(cur ^ 1, j0 + 64);
    const char* Kr = sm + cur * 24576;
    const char* Ki = Kr + 8192;
    const char* Vt = Kr + 16384;

    // S^T = Kr@Qr^T + Ki@Qi^T  (two 32-k blocks, interleaved for MFMA ILP)
    f32x16 s0, s1;
#pragma unroll
    for (int r = 0; r < 16; r++) { s0[r] = 0.f; s1[r] = 0.f; }
#pragma unroll
    for (int c = 0; c < 4; c++) {
      int off = (c * 32 + hi * 16) ^ swz;
      bf16x8 a0r = *(const bf16x8*)(Kr + lo * 128 + off);
      bf16x8 a0i = *(const bf16x8*)(Ki + lo * 128 + off);
      bf16x8 a1r = *(const bf16x8*)(Kr + (32 + lo) * 128 + off);
      bf16x8 a1i = *(const bf16x8*)(Ki + (32 + lo) * 128 + off);
      __builtin_amdgcn_s_setprio(1);
      s0 = __builtin_amdgcn_mfma_f32_32x32x16_bf16(a0r, fqr[c], s0, 0, 0, 0);
      s1 = __builtin_amdgcn_mfma_f32_32x32x16_bf16(a1r, fqr[c], s1, 0, 0, 0);
      s0 = __builtin_amdgcn_mfma_f32_32x32x16_bf16(a0i, fqi[c], s0, 0, 0, 0);
      s1 = __builtin_amdgcn_mfma_f32_32x32x16_bf16(a1i, fqi[c], s1, 0, 0, 0);
      __builtin_amdgcn_s_setprio(0);
    }
    // banded mask: k <= i-129 -> -inf   (only ever the first tiles of a block)
    if (j0 <= i0w - 98) {
#pragma unroll
      for (int r = 0; r < 16; r++) {
        int kk = j0 + (r & 3) + ((r >> 2) << 3) + (hi << 2);
        if (kk <= irow - 129) s0[r] = -3e38f;
        if (kk + 32 <= irow - 129) s1[r] = -3e38f;
      }
    }
    // row max (tree; lane owns q=lo, partner lane lo+32 mirrors)
    float m4[8];
#pragma unroll
    for (int j = 0; j < 4; j++)
      m4[j] = fmaxf(fmaxf(s0[4 * j], s0[4 * j + 1]), fmaxf(s0[4 * j + 2], s0[4 * j + 3]));
#pragma unroll
    for (int j = 0; j < 4; j++)
      m4[4 + j] = fmaxf(fmaxf(s1[4 * j], s1[4 * j + 1]), fmaxf(s1[4 * j + 2], s1[4 * j + 3]));
    float pmax = fmaxf(fmaxf(fmaxf(m4[0], m4[1]), fmaxf(m4[2], m4[3])),
                       fmaxf(fmaxf(m4[4], m4[5]), fmaxf(m4[6], m4[7])));
    pmax = fmaxf(pmax, __shfl_xor(pmax, 32));

    // defer-max (T13): rescale only when max grew by > 11.5 (log2) ~= e^8
    if (!__all(pmax <= m_run + 11.5f)) {
      float mnew = fmaxf(m_run, pmax);
      float scl = exp2f(m_run - mnew);
#pragma unroll
      for (int r = 0; r < 16; r++) { oa0[r] *= scl; oa1[r] *= scl; }
      l_run *= scl;
      m_run = mnew;
    }

    // P = exp2(S - m), in place; 4-way partial sums
    float ps0 = 0.f, ps1 = 0.f, ps2 = 0.f, ps3 = 0.f;
#pragma unroll
    for (int r = 0; r < 16; r += 4) {
      s0[r] = exp2f(s0[r] - m_run);     ps0 += s0[r];
      s0[r + 1] = exp2f(s0[r + 1] - m_run); ps1 += s0[r + 1];
      s0[r + 2] = exp2f(s0[r + 2] - m_run); ps2 += s0[r + 2];
      s0[r + 3] = exp2f(s0[r + 3] - m_run); ps3 += s0[r + 3];
    }
#pragma unroll
    for (int r = 0; r < 16; r += 4) {
      s1[r] = exp2f(s1[r] - m_run);     ps0 += s1[r];
      s1[r + 1] = exp2f(s1[r + 1] - m_run); ps1 += s1[r + 1];
      s1[r + 2] = exp2f(s1[r + 2] - m_run); ps2 += s1[r + 2];
      s1[r + 3] = exp2f(s1[r + 3] - m_run); ps3 += s1[r + 3];
    }
    float psum = (ps0 + ps1) + (ps2 + ps3);
    psum += __shfl_xor(psum, 32);
    l_run += psum;

    // assemble P^T B-fragments in-register (cvt_pk + permlane32_swap)
    bf16x8 pf0, pf1, pf2, pf3;
    mkfrag((const float*)&s0, pf0, pf1);
    mkfrag((const float*)&s1, pf2, pf3);

    // O^T += V^T @ P^T
#pragma unroll
    for (int kc = 0; kc < 4; kc++) {
      int off = (kc * 32 + hi * 16) ^ swz;
      bf16x8 av0 = *(const bf16x8*)(Vt + lo * 128 + off);
      bf16x8 av1 = *(const bf16x8*)(Vt + (32 + lo) * 128 + off);
      bf16x8 pk = (kc == 0) ? pf0 : (kc == 1) ? pf1 : (kc == 2) ? pf2 : pf3;
      __builtin_amdgcn_s_setprio(1);
      oa0 = __builtin_amdgcn_mfma_f32_32x32x16_bf16(av0, pk, oa0, 0, 0, 0);
      oa1 = __builtin_amdgcn_mfma_f32_32x32x16_bf16(av1, pk, oa1, 0, 0, 0);
      __builtin_amdgcn_s_setprio(0);
    }
    __syncthreads();
    cur ^= 1;
  }

  // write o[b][l][h*64+d] bf16; lane holds column q=lo of O^T
  float rl = 1.0f / l_run;
  u16* orow = obf + ((size_t)(bb * 4096 + irow) << 9) + hh * 64;
#pragma unroll
  for (int g = 0; g < 4; g++) {
    ushort4 v0 = make_ushort4(f2bf(oa0[4 * g] * rl), f2bf(oa0[4 * g + 1] * rl),
                              f2bf(oa0[4 * g + 2] * rl), f2bf(oa0[4 * g + 3] * rl));
    *(ushort4*)(orow + g * 8 + hi * 4) = v0;
    ushort4 v1 = make_ushort4(f2bf(oa1[4 * g] * rl), f2bf(oa1[4 * g + 1] * rl),
                              f2bf(oa1[4 * g + 2] * rl), f2bf(oa1[4 * g + 3] * rl));
    *(ushort4*)(orow + 32 + g * 8 + hi * 4) = v1;
  }
}

// ---------------- launch ----------------
extern "C" void kernel_launch(void* const* d_in, const int* in_sizes, int n_in,
                              void* d_out, int out_size, void* d_ws, size_t ws_size,
                              hipStream_t stream) {
  (void)in_sizes; (void)n_in; (void)out_size; (void)ws_size;
  const float* q = (const float*)d_in[0];
  const float* k = (const float*)d_in[1];
  const float* v = (const float*)d_in[2];
  char* ws = (char*)d_ws;
  u16* wcat = (u16*)(ws + 0x000000);     // 3584x512 bf16
  float* bcat = (float*)(ws + 0x400000); // 3584 f32
  u16* xq  = (u16*)(ws + 0x500000);
  u16* xk  = (u16*)(ws + 0xD00000);
  u16* xv  = (u16*)(ws + 0x1500000);
  u16* qrb = (u16*)(ws + 0x1D00000);
  u16* qib = (u16*)(ws + 0x2500000);
  u16* krb = (u16*)(ws + 0x2D00000);
  u16* kib = (u16*)(ws + 0x3500000);
  u16* vtb = (u16*)(ws + 0x3D00000);
  u16* obf = xq;  // xq dead after proj; reuse for attention output
  float* out = (float*)d_out;

  cvt_x_kernel<<<2048, 256, 0, stream>>>(q, k, v, xq, xk, xv);

  CPtrs cp;
  cp.w[0] = (const float*)d_in[3];  cp.w[1] = (const float*)d_in[4];
  cp.w[2] = (const float*)d_in[7];  cp.w[3] = (const float*)d_in[8];
  cp.w[4] = (const float*)d_in[11]; cp.w[5] = (const float*)d_in[15]; cp.w[6] = (const float*)d_in[16];
  cp.b[0] = (const float*)d_in[5];  cp.b[1] = (const float*)d_in[6];
  cp.b[2] = (const float*)d_in[9];  cp.b[3] = (const float*)d_in[10];
  cp.b[4] = (const float*)d_in[13]; cp.b[5] = (const float*)d_in[17]; cp.b[6] = (const float*)d_in[18];
  cvt_wb_kernel<<<448, 256, 0, stream>>>(cp, wcat, bcat);

  proj_kernel<<<dim3(20, 64), 256, 0, stream>>>(xq, xk, xv, wcat, bcat, qrb, qib, krb, kib, vtb);
  attn_kernel<<<512, 256, 0, stream>>>(qrb, qib, krb, kib, vtb, obf);
  oproj_kernel<<<dim3(8, 64), 256, 0, stream>>>(obf, wcat, bcat, out);
}

// Round 4
// 197.514 us; speedup vs baseline: 1.0619x; 1.0176x over previous
//
#include <hip/hip_runtime.h>

// ComplexMultiheadAttention, MI355X/gfx950.
// Pipeline: cvt(f32->bf16) -> proj GEMMs (qr,qi,kr,ki,vr^T) -> banded flash attn -> out proj.
// B=2, L=4096, E=512, H=8, D=64, W=128 (mask: j <= i-129 is -inf; NO causal/upper mask).
// Softmax runs in log2 domain: 0.125*log2(e) folded into q projection, exp2f in-kernel.
// Attn is software-pipelined: QK(t+1) issues before softmax/PV(t); 3-buffer LDS rotation.

typedef unsigned short u16;
typedef unsigned int u32;
typedef __attribute__((ext_vector_type(8))) short bf16x8;
typedef __attribute__((ext_vector_type(4))) float f32x4;
typedef __attribute__((ext_vector_type(16))) float f32x16;
typedef __attribute__((ext_vector_type(4))) u32 u32x4;

#define L_ 4096
#define E_ 512
#define M_ 8192  // B*L

__device__ __forceinline__ u16 f2bf(float f) {
  union { float f; u32 u; } v; v.f = f;
  return (u16)((v.u + 0x7FFFu + ((v.u >> 16) & 1u)) >> 16);  // RNE
}

__device__ __forceinline__ void gll16(const void* g, void* l) {
  __builtin_amdgcn_global_load_lds(
      (const __attribute__((address_space(1))) u32*)g,
      (__attribute__((address_space(3))) u32*)l, 16, 0, 0);
}

// ---------------- conversion kernels ----------------
__global__ void cvt_x_kernel(const float* __restrict__ q, const float* __restrict__ k,
                             const float* __restrict__ v,
                             u16* __restrict__ xq, u16* __restrict__ xk, u16* __restrict__ xv) {
  const int total = 3 * (M_ * E_ / 4);  // float4 units, 1<<20 per matrix
  int stride = gridDim.x * blockDim.x;
  for (int u = blockIdx.x * blockDim.x + threadIdx.x; u < total; u += stride) {
    int mat = u >> 20, e = u & ((1 << 20) - 1);
    const float4 f = ((const float4*)(mat == 0 ? q : mat == 1 ? k : v))[e];
    ushort4 o = make_ushort4(f2bf(f.x), f2bf(f.y), f2bf(f.z), f2bf(f.w));
    *(ushort4*)((mat == 0 ? xq : mat == 1 ? xk : xv) + (size_t)e * 4) = o;
  }
}

struct CPtrs { const float* w[7]; const float* b[7]; };

__global__ void cvt_wb_kernel(CPtrs p, u16* __restrict__ wcat, float* __restrict__ bcat) {
  // wcat rows: [qWr|qWi|kWr|kWi|vWr|oWr|oWi], each 512x512. bcat matching biases.
  const int total = 7 * (E_ * E_ / 4);  // 65536 float4 per matrix
  int stride = gridDim.x * blockDim.x;
  int t0 = blockIdx.x * blockDim.x + threadIdx.x;
  for (int u = t0; u < total; u += stride) {
    int wi = u >> 16, e = u & 65535;
    const float4 f = ((const float4*)p.w[wi])[e];
    ushort4 o = make_ushort4(f2bf(f.x), f2bf(f.y), f2bf(f.z), f2bf(f.w));
    *(ushort4*)(wcat + (size_t)wi * 262144 + (size_t)e * 4) = o;
  }
  for (int j = t0; j < 3584; j += stride) bcat[j] = p.b[j >> 9][j & 511];
}

// ---------------- 128x128 bf16 GEMM mainloop (C = A @ W^T), K=512, BK=32 ----------------
__device__ __forceinline__ void gemm128_main(const u16* __restrict__ A, const u16* __restrict__ Bw,
                                             int m0, int n0w, char* sm, f32x4 acc[4][4]) {
  int tid = threadIdx.x;
  int lane = tid & 63, w = tid >> 6;
  int wm = w >> 1, wn = w & 1;
#pragma unroll
  for (int a = 0; a < 4; a++)
#pragma unroll
    for (int b = 0; b < 4; b++)
#pragma unroll
      for (int j = 0; j < 4; j++) acc[a][b][j] = 0.f;

  auto stage = [&](int buf, int ks) {
    char* dst = sm + buf * 16384;
#pragma unroll
    for (int n = 0; n < 2; n++) {
      int u = n * 256 + tid;
      int row = u >> 2, c = u & 3;
      int so = (c ^ (row & 3)) * 16;  // pre-swizzled source chunk (LDS stays linear)
      int ldso = (n * 256 + w * 64) * 16;
      gll16((const char*)(A + (size_t)(m0 + row) * 512 + ks * 32) + so, dst + ldso);
      gll16((const char*)(Bw + (size_t)(n0w + row) * 512 + ks * 32) + so, dst + 8192 + ldso);
    }
  };

  stage(0, 0);
  __syncthreads();
  int cur = 0;
  for (int ks = 0; ks < 16; ks++) {
    if (ks < 15) stage(cur ^ 1, ks + 1);
    const char* as = sm + cur * 16384;
    const char* bs = as + 8192;
    bf16x8 af[4], bfr[4];
#pragma unroll
    for (int i = 0; i < 4; i++) {
      int ra = wm * 64 + i * 16 + (lane & 15);
      af[i] = *(const bf16x8*)(as + ra * 64 + (((lane >> 4) * 16) ^ ((ra & 3) << 4)));
      int rb = wn * 64 + i * 16 + (lane & 15);
      bfr[i] = *(const bf16x8*)(bs + rb * 64 + (((lane >> 4) * 16) ^ ((rb & 3) << 4)));
    }
    __builtin_amdgcn_s_setprio(1);
#pragma unroll
    for (int mt = 0; mt < 4; mt++)
#pragma unroll
      for (int nt = 0; nt < 4; nt++)
        acc[mt][nt] = __builtin_amdgcn_mfma_f32_16x16x32_bf16(af[mt], bfr[nt], acc[mt][nt], 0, 0, 0);
    __builtin_amdgcn_s_setprio(0);
    __syncthreads();
    cur ^= 1;
  }
}

// ---------------- projection kernel (q,k,v jobs) ----------------
__global__ __launch_bounds__(256) void proj_kernel(
    const u16* __restrict__ xq, const u16* __restrict__ xk, const u16* __restrict__ xv,
    const u16* __restrict__ wcat, const float* __restrict__ bcat,
    u16* __restrict__ qrb, u16* __restrict__ qib,
    u16* __restrict__ krb, u16* __restrict__ kib, u16* __restrict__ vtb) {
  __shared__ alignas(16) char sm[32768];
  int bx = blockIdx.x, by = blockIdx.y;  // bx<8: q (N=1024), bx<16: k, else v (N=512)
  const u16* A = bx < 8 ? xq : (bx < 16 ? xk : xv);
  int m0 = by * 128, n0w = bx * 128;
  f32x4 acc[4][4];
  gemm128_main(A, wcat, m0, n0w, sm, acc);

  int lane = threadIdx.x & 63, w = threadIdx.x >> 6;
  int wm = w >> 1, wn = w & 1;
  int lL = lane & 15, lH = lane >> 4;
#pragma unroll
  for (int mt = 0; mt < 4; mt++) {
#pragma unroll
    for (int nt = 0; nt < 4; nt++) {
      int n = n0w + wn * 64 + nt * 16 + lL;  // global wcat row
      float bias = bcat[n];
      int e = n & 511;
#pragma unroll
      for (int j = 0; j < 4; j++) {
        int m = m0 + wm * 64 + mt * 16 + lH * 4 + j;
        float val = acc[mt][nt][j] + bias;
        int bb = m >> 12, ll = m & 4095;
        if (bx < 16) {
          if (bx < 8) val *= 0.18033688011112042f;  // 1/sqrt(D) * log2(e) folded into q
          u16* dst = (bx < 8) ? ((n & 512) ? qib : qrb) : ((n & 512) ? kib : krb);
          dst[((size_t)((bb * 8 + (e >> 6)) * 4096 + ll) << 6) + (e & 63)] = f2bf(val);
        } else {
          // vr stored transposed: VT[bh][d][l]
          vtb[((size_t)((bb * 8 + (e >> 6)) * 64 + (e & 63)) << 12) + ll] = f2bf(val);
        }
      }
    }
  }
}

// ---------------- output projection kernel ----------------
__global__ __launch_bounds__(256) void oproj_kernel(
    const u16* __restrict__ obf, const u16* __restrict__ wcat, const float* __restrict__ bcat,
    float* __restrict__ out) {
  __shared__ alignas(16) char sm[32768];
  int bx = blockIdx.x, by = blockIdx.y;
  int m0 = by * 128, n0w = 2560 + bx * 128;
  f32x4 acc[4][4];
  gemm128_main(obf, wcat, m0, n0w, sm, acc);

  int lane = threadIdx.x & 63, w = threadIdx.x >> 6;
  int wm = w >> 1, wn = w & 1;
  int lL = lane & 15, lH = lane >> 4;
#pragma unroll
  for (int mt = 0; mt < 4; mt++) {
#pragma unroll
    for (int nt = 0; nt < 4; nt++) {
      int n = n0w + wn * 64 + nt * 16 + lL;
      float bias = bcat[n];
      int nn = n - 2560;
      // out_r at [0, 4194304), out_i at [4194304, 8388608)  (B*L*E = 4194304 each)
      float* dst = out + ((nn & 512) ? 4194304 : 0) + (nn & 511);
#pragma unroll
      for (int j = 0; j < 4; j++) {
        int m = m0 + wm * 64 + mt * 16 + lH * 4 + j;
        dst[(size_t)m * 512] = acc[mt][nt][j] + bias;
      }
    }
  }
}

// ---------------- banded flash attention (software-pipelined) ----------------
// QB=128 (4 waves x 32 q-rows), KB=64, D=64. Swapped QK^T: S^T = mfma(K, Q).
// S^T layout (32x32x16): col=lane&31 (=q), row=(r&3)+8*(r>>2)+4*(lane>>5) (=k).
// Schedule per iter: stage(t+2) -> QK(t+1) [MFMA] -> softmax(t)+mkfrag [VALU overlap]
//                    -> PV(t) -> barrier. 3 LDS buffers rotate; ntiles is always even.
__global__ __launch_bounds__(256, 2) void attn_kernel(
    const u16* __restrict__ qrb, const u16* __restrict__ qib,
    const u16* __restrict__ krb, const u16* __restrict__ kib,
    const u16* __restrict__ vtb, u16* __restrict__ obf) {
  __shared__ alignas(16) char sm[3 * 24576];  // 3 x (Kr 8K | Ki 8K | VT 8K)
  int bid = blockIdx.x;
  int bh = bid & 15;          // bh pins to XCD (bid%8==bh%8)
  int q2 = bid >> 4;          // 0..31
  int qt = (q2 < 16) ? q2 : (47 - q2);  // pair heavy+light blocks per CU (work ~const)
  int bb = bh >> 3, hh = bh & 7;
  int i0 = qt << 7;
  int tid = threadIdx.x;
  int lane = tid & 63, w = tid >> 6;    // w in 0..3
  int lo = lane & 31, hi = lane >> 5;
  int i0w = i0 + w * 32;
  int irow = i0w + lo;

  // Q fragments (B-operand): lane holds Q[q=lo][d = c*16 + hi*8 + i]
  bf16x8 fqr[4], fqi[4];
  {
    const u16* qp = qrb + ((size_t)(bh * 4096 + irow) << 6) + hi * 8;
    const u16* qip = qib + ((size_t)(bh * 4096 + irow) << 6) + hi * 8;
#pragma unroll
    for (int c = 0; c < 4; c++) {
      fqr[c] = *(const bf16x8*)(qp + c * 16);
      fqi[c] = *(const bf16x8*)(qip + c * 16);
    }
  }

  f32x16 oa0, oa1;  // O^T[d][q]: oa0 d=0..31, oa1 d=32..63 (col=q=lo)
#pragma unroll
  for (int r = 0; r < 16; r++) { oa0[r] = 0.f; oa1[r] = 0.f; }
  float m_run = -1e30f, l_run = 0.f;

  int jstart = (i0 >= 128) ? (i0 - 128) : 0;
  int ntiles = (4096 - jstart) >> 6;  // always even, >= 4

  auto stage = [&](char* dst, int j0) {
#pragma unroll
    for (int n = 0; n < 2; n++) {
      int u = n * 256 + tid;           // 0..511 over 64 rows x 8 chunks
      int row = u >> 3, c = u & 7;
      int so = (c ^ (row & 7)) * 16;   // pre-swizzled source; LDS linear
      int ldso = (n * 256 + w * 64) * 16;  // wave-uniform LDS base
      size_t krow = ((size_t)(bh * 4096 + j0 + row) << 6);
      gll16((const char*)(krb + krow) + so, dst + ldso);
      gll16((const char*)(kib + krow) + so, dst + 8192 + ldso);
      size_t vrow = ((size_t)(bh * 64 + row) << 12) + j0;
      gll16((const char*)(vtb + vrow) + so, dst + 16384 + ldso);
    }
  };

  int swz = (lo & 7) << 4;

  // QK^T for one tile: S^T = Kr@Qr^T + Ki@Qi^T
  auto qk = [&](const char* Kbase, f32x16& s0, f32x16& s1) {
    const char* Kr = Kbase;
    const char* Ki = Kbase + 8192;
#pragma unroll
    for (int r = 0; r < 16; r++) { s0[r] = 0.f; s1[r] = 0.f; }
#pragma unroll
    for (int c = 0; c < 4; c++) {
      int off = (c * 32 + hi * 16) ^ swz;
      bf16x8 a0r = *(const bf16x8*)(Kr + lo * 128 + off);
      bf16x8 a0i = *(const bf16x8*)(Ki + lo * 128 + off);
      bf16x8 a1r = *(const bf16x8*)(Kr + (32 + lo) * 128 + off);
      bf16x8 a1i = *(const bf16x8*)(Ki + (32 + lo) * 128 + off);
      __builtin_amdgcn_s_setprio(1);
      s0 = __builtin_amdgcn_mfma_f32_32x32x16_bf16(a0r, fqr[c], s0, 0, 0, 0);
      s1 = __builtin_amdgcn_mfma_f32_32x32x16_bf16(a1r, fqr[c], s1, 0, 0, 0);
      s0 = __builtin_amdgcn_mfma_f32_32x32x16_bf16(a0i, fqi[c], s0, 0, 0, 0);
      s1 = __builtin_amdgcn_mfma_f32_32x32x16_bf16(a1i, fqi[c], s1, 0, 0, 0);
      __builtin_amdgcn_s_setprio(0);
    }
  };

  auto cvtpk = [](float a, float b) -> u32 {
    u32 r;
    asm("v_cvt_pk_bf16_f32 %0, %1, %2" : "=v"(r) : "v"(a), "v"(b));
    return r;
  };
  auto mkfrag = [&](const float* p, bf16x8& fA, bf16x8& fB) {
    u32 x0 = cvtpk(p[0], p[1]), y0 = cvtpk(p[4], p[5]);
    u32 x1 = cvtpk(p[2], p[3]), y1 = cvtpk(p[6], p[7]);
    u32 x2 = cvtpk(p[8], p[9]), y2 = cvtpk(p[12], p[13]);
    u32 x3 = cvtpk(p[10], p[11]), y3 = cvtpk(p[14], p[15]);
    asm("v_permlane32_swap_b32 %0, %1" : "+v"(x0), "+v"(y0));
    asm("v_permlane32_swap_b32 %0, %1" : "+v"(x1), "+v"(y1));
    asm("v_permlane32_swap_b32 %0, %1" : "+v"(x2), "+v"(y2));
    asm("v_permlane32_swap_b32 %0, %1" : "+v"(x3), "+v"(y3));
    u32x4 a; a[0] = x0; a[1] = x1; a[2] = y0; a[3] = y1;
    u32x4 b; b[0] = x2; b[1] = x3; b[2] = y2; b[3] = y3;
    fA = __builtin_bit_cast(bf16x8, a);
    fB = __builtin_bit_cast(bf16x8, b);
  };

  // mask + online softmax + P-frag + PV for tile at j0 (LDS base = Kbase)
  auto smpv = [&](const char* Kbase, int j0, f32x16& s0, f32x16& s1) {
    // banded mask: k <= i-129 -> -inf (only the first 1-2 tiles of a block)
    if (j0 <= i0w - 98) {
#pragma unroll
      for (int r = 0; r < 16; r++) {
        int kk = j0 + (r & 3) + ((r >> 2) << 3) + (hi << 2);
        if (kk <= irow - 129) s0[r] = -3e38f;
        if (kk + 32 <= irow - 129) s1[r] = -3e38f;
      }
    }
    // row max (tree; lane owns q=lo, partner lane lo+32 mirrors)
    float m4[8];
#pragma unroll
    for (int j = 0; j < 4; j++)
      m4[j] = fmaxf(fmaxf(s0[4 * j], s0[4 * j + 1]), fmaxf(s0[4 * j + 2], s0[4 * j + 3]));
#pragma unroll
    for (int j = 0; j < 4; j++)
      m4[4 + j] = fmaxf(fmaxf(s1[4 * j], s1[4 * j + 1]), fmaxf(s1[4 * j + 2], s1[4 * j + 3]));
    float pmax = fmaxf(fmaxf(fmaxf(m4[0], m4[1]), fmaxf(m4[2], m4[3])),
                       fmaxf(fmaxf(m4[4], m4[5]), fmaxf(m4[6], m4[7])));
    pmax = fmaxf(pmax, __shfl_xor(pmax, 32));

    // defer-max (T13): rescale only when max grew by > 11.5 (log2) ~= e^8
    if (!__all(pmax <= m_run + 11.5f)) {
      float mnew = fmaxf(m_run, pmax);
      float scl = exp2f(m_run - mnew);
#pragma unroll
      for (int r = 0; r < 16; r++) { oa0[r] *= scl; oa1[r] *= scl; }
      l_run *= scl;
      m_run = mnew;
    }

    // P = exp2(S - m), in place; 4-way partial sums
    float ps0 = 0.f, ps1 = 0.f, ps2 = 0.f, ps3 = 0.f;
#pragma unroll
    for (int r = 0; r < 16; r += 4) {
      s0[r] = exp2f(s0[r] - m_run);     ps0 += s0[r];
      s0[r + 1] = exp2f(s0[r + 1] - m_run); ps1 += s0[r + 1];
      s0[r + 2] = exp2f(s0[r + 2] - m_run); ps2 += s0[r + 2];
      s0[r + 3] = exp2f(s0[r + 3] - m_run); ps3 += s0[r + 3];
    }
#pragma unroll
    for (int r = 0; r < 16; r += 4) {
      s1[r] = exp2f(s1[r] - m_run);     ps0 += s1[r];
      s1[r + 1] = exp2f(s1[r + 1] - m_run); ps1 += s1[r + 1];
      s1[r + 2] = exp2f(s1[r + 2] - m_run); ps2 += s1[r + 2];
      s1[r + 3] = exp2f(s1[r + 3] - m_run); ps3 += s1[r + 3];
    }
    float psum = (ps0 + ps1) + (ps2 + ps3);
    psum += __shfl_xor(psum, 32);
    l_run += psum;

    // assemble P^T B-fragments in-register (cvt_pk + permlane32_swap)
    bf16x8 pf0, pf1, pf2, pf3;
    mkfrag((const float*)&s0, pf0, pf1);
    mkfrag((const float*)&s1, pf2, pf3);

    // O^T += V^T @ P^T
    const char* Vt = Kbase + 16384;
#pragma unroll
    for (int kc = 0; kc < 4; kc++) {
      int off = (kc * 32 + hi * 16) ^ swz;
      bf16x8 av0 = *(const bf16x8*)(Vt + lo * 128 + off);
      bf16x8 av1 = *(const bf16x8*)(Vt + (32 + lo) * 128 + off);
      bf16x8 pk = (kc == 0) ? pf0 : (kc == 1) ? pf1 : (kc == 2) ? pf2 : pf3;
      __builtin_amdgcn_s_setprio(1);
      oa0 = __builtin_amdgcn_mfma_f32_32x32x16_bf16(av0, pk, oa0, 0, 0, 0);
      oa1 = __builtin_amdgcn_mfma_f32_32x32x16_bf16(av1, pk, oa1, 0, 0, 0);
      __builtin_amdgcn_s_setprio(0);
    }
  };

  // ---- pipelined main loop: 3 rotating LDS buffers, 2 S-register sets ----
  char* cur = sm;
  char* nxt = sm + 24576;
  char* nx2 = sm + 49152;

  stage(cur, jstart);
  stage(nxt, jstart + 64);
  __syncthreads();

  f32x16 sA0, sA1, sB0, sB1;
  qk(cur, sA0, sA1);  // QK(0)

  for (int t = 0; t < ntiles; t += 2) {
    int j0 = jstart + (t << 6);
    // even half: tile t (state A), QK(t+1) into B
    if (t + 2 < ntiles) stage(nx2, j0 + 128);
    qk(nxt, sB0, sB1);          // t+1 < ntiles always (ntiles even)
    smpv(cur, j0, sA0, sA1);
    __syncthreads();
    { char* tmp = cur; cur = nxt; nxt = nx2; nx2 = tmp; }
    // odd half: tile t+1 (state B), QK(t+2) into A
    if (t + 3 < ntiles) stage(nx2, j0 + 192);
    if (t + 2 < ntiles) qk(nxt, sA0, sA1);
    smpv(cur, j0 + 64, sB0, sB1);
    __syncthreads();
    { char* tmp = cur; cur = nxt; nxt = nx2; nx2 = tmp; }
  }

  // write o[b][l][h*64+d] bf16; lane holds column q=lo of O^T
  float rl = 1.0f / l_run;
  u16* orow = obf + ((size_t)(bb * 4096 + irow) << 9) + hh * 64;
#pragma unroll
  for (int g = 0; g < 4; g++) {
    ushort4 v0 = make_ushort4(f2bf(oa0[4 * g] * rl), f2bf(oa0[4 * g + 1] * rl),
                              f2bf(oa0[4 * g + 2] * rl), f2bf(oa0[4 * g + 3] * rl));
    *(ushort4*)(orow + g * 8 + hi * 4) = v0;
    ushort4 v1 = make_ushort4(f2bf(oa1[4 * g] * rl), f2bf(oa1[4 * g + 1] * rl),
                              f2bf(oa1[4 * g + 2] * rl), f2bf(oa1[4 * g + 3] * rl));
    *(ushort4*)(orow + 32 + g * 8 + hi * 4) = v1;
  }
}

// ---------------- launch ----------------
extern "C" void kernel_launch(void* const* d_in, const int* in_sizes, int n_in,
                              void* d_out, int out_size, void* d_ws, size_t ws_size,
                              hipStream_t stream) {
  (void)in_sizes; (void)n_in; (void)out_size; (void)ws_size;
  const float* q = (const float*)d_in[0];
  const float* k = (const float*)d_in[1];
  const float* v = (const float*)d_in[2];
  char* ws = (char*)d_ws;
  u16* wcat = (u16*)(ws + 0x000000);     // 3584x512 bf16
  float* bcat = (float*)(ws + 0x400000); // 3584 f32
  u16* xq  = (u16*)(ws + 0x500000);
  u16* xk  = (u16*)(ws + 0xD00000);
  u16* xv  = (u16*)(ws + 0x1500000);
  u16* qrb = (u16*)(ws + 0x1D00000);
  u16* qib = (u16*)(ws + 0x2500000);
  u16* krb = (u16*)(ws + 0x2D00000);
  u16* kib = (u16*)(ws + 0x3500000);
  u16* vtb = (u16*)(ws + 0x3D00000);
  u16* obf = xq;  // xq dead after proj; reuse for attention output
  float* out = (float*)d_out;

  cvt_x_kernel<<<2048, 256, 0, stream>>>(q, k, v, xq, xk, xv);

  CPtrs cp;
  cp.w[0] = (const float*)d_in[3];  cp.w[1] = (const float*)d_in[4];
  cp.w[2] = (const float*)d_in[7];  cp.w[3] = (const float*)d_in[8];
  cp.w[4] = (const float*)d_in[11]; cp.w[5] = (const float*)d_in[15]; cp.w[6] = (const float*)d_in[16];
  cp.b[0] = (const float*)d_in[5];  cp.b[1] = (const float*)d_in[6];
  cp.b[2] = (const float*)d_in[9];  cp.b[3] = (const float*)d_in[10];
  cp.b[4] = (const float*)d_in[13]; cp.b[5] = (const float*)d_in[17]; cp.b[6] = (const float*)d_in[18];
  cvt_wb_kernel<<<448, 256, 0, stream>>>(cp, wcat, bcat);

  proj_kernel<<<dim3(20, 64), 256, 0, stream>>>(xq, xk, xv, wcat, bcat, qrb, qib, krb, kib, vtb);
  attn_kernel<<<512, 256, 0, stream>>>(qrb, qib, krb, kib, vtb, obf);
  oproj_kernel<<<dim3(8, 64), 256, 0, stream>>>(obf, wcat, bcat, out);
}